// Round 3
// baseline (280.441 us; speedup 1.0000x reference)
//
#include <hip/hip_runtime.h>
#include <stdint.h>

#define B_    32768
#define C_    64
#define D_    8
#define K15_  15
#define K16_  16
#define OUT_  512

typedef _Float16 half8 __attribute__((ext_vector_type(8)));

// workspace layout (bytes)
#define AMAP_OFF  0
#define AMAP_SZ   32768                  // uint8 argmax per 15-bit code
#define S64_OFF   32768                  // fp64 S, k-major: S64[c][k][d], 64*15*8
#define S64_SZ    (64 * 15 * 8 * 8)      // 61440
#define T64_OFF   (S64_OFF + S64_SZ)     // 94208
#define T64_SZ    (64 * 15 * 8)          // 7680
#define IDX_OFF   (T64_OFF + T64_SZ)     // 101888
#define IDX_SZ    (B_ * C_)              // 2 MB
#define PC_OFF    (IDX_OFF + IDX_SZ)     // 2199040
#define PC_SZ     (B_ * 32)              // 1 MB
#define PTAB_OFF  (PC_OFF + PC_SZ)       // 3247616 (16B aligned)
#define PTAB_SZ   (32 * 256 * 512 * 2)   // 8388608  P[pair][t0t1][512] fp16
#define WS_NEED   ((size_t)PTAB_OFF + PTAB_SZ)
#define WS_FALLBACK ((size_t)PC_OFF + PC_SZ)

// ---------------------------------------------------------------------------
// amap[code] = argmax_j sum_k (+-1)*H[k][j] (fp64)
// ---------------------------------------------------------------------------
__global__ __launch_bounds__(256) void k_amap(const float* __restrict__ H,
                                              uint8_t* __restrict__ amap) {
    int code = blockIdx.x * 256 + threadIdx.x;
    double h[K16_];
#pragma unroll
    for (int j = 0; j < K16_; ++j) h[j] = 0.0;
#pragma unroll
    for (int k = 0; k < K15_; ++k) {
        double s = ((code >> k) & 1) ? 1.0 : -1.0;
#pragma unroll
        for (int j = 0; j < K16_; ++j) h[j] += s * (double)H[k * K16_ + j];
    }
    double best = h[0];
    int bi = 0;
#pragma unroll
    for (int j = 1; j < K16_; ++j) {
        if (h[j] > best) { best = h[j]; bi = j; }
    }
    amap[code] = (uint8_t)bi;
}

// ---------------------------------------------------------------------------
// prep: S64[c][k][d] = (double)S[c][d][k]   (k-major so each k is 64B chunk
// -> s_load_dwordx16 in k_codes2), T64[c][k] = (double)T[c][k].
// ---------------------------------------------------------------------------
__global__ __launch_bounds__(256) void k_prep(const float* __restrict__ S,
                                              const float* __restrict__ T,
                                              double* __restrict__ S64,
                                              double* __restrict__ T64) {
    for (int i = threadIdx.x; i < 64 * 15 * 8; i += 256) {
        int c = i / 120;
        int r = i - c * 120;     // r = k*8 + d
        int k = r >> 3;
        int d = r & 7;
        S64[i] = (double)S[c * 120 + d * 15 + k];
    }
    for (int i = threadIdx.x; i < 64 * 15; i += 256) T64[i] = (double)T[i];
}

// ---------------------------------------------------------------------------
// k_codes2: block = 256 thr (4 waves), 64 batches per block.
// Stage x into LDS transposed (xls[cl][b]), then wave<->channel, lane<->batch:
// S/T are wave-uniform -> scalar loads; 8 LDS reads per (b,c) instead of 135.
// fp64 dot products (sign safety). Produces idx bytes + packed pair codes.
// ---------------------------------------------------------------------------
#define XSTRIDE 585   // odd -> conflict-free lane*9 reads and staged writes
__global__ __launch_bounds__(256) void k_codes2(const float* __restrict__ x,
                                                const double* __restrict__ S64,
                                                const double* __restrict__ T64,
                                                const uint8_t* __restrict__ amap,
                                                uint8_t* __restrict__ idxo,
                                                uint8_t* __restrict__ pco) {
    __shared__ float xls[32 * XSTRIDE];     // 32 ch x (64 b x 9) floats
    __shared__ uint8_t idsh[64 * 68];       // idx per (b, c), row pad 68

    int b0 = blockIdx.x * 64;
    int lane = threadIdx.x & 63;
    int wv = __builtin_amdgcn_readfirstlane(threadIdx.x >> 6);

    for (int half = 0; half < 2; ++half) {
        __syncthreads();
        // stage 64 rows x 256 floats (this half's 32 channels)
#pragma unroll
        for (int t = 0; t < 16; ++t) {
            int e = t * 256 + threadIdx.x;      // float4 index in [64][64]
            int b = e >> 6;
            int j4 = e & 63;
            float4 v = ((const float4*)(x + (size_t)(b0 + b) * 512 +
                                        half * 256))[j4];
            int cl = j4 >> 1;
            int d0 = (j4 & 1) * 4;
            float* dst = &xls[cl * XSTRIDE + b * 9 + d0];
            dst[0] = v.x; dst[1] = v.y; dst[2] = v.z; dst[3] = v.w;
        }
        __syncthreads();
        // compute: wave wv -> channels cl = wv, wv+4, ..., wv+28
        for (int i = 0; i < 8; ++i) {
            int cl = wv + i * 4;                 // wave-uniform
            int c = half * 32 + cl;
            const double* Sc = S64 + c * 120;    // k-major: Sc[k*8+d]
            const double* Tc = T64 + c * 15;
            double xd[8];
#pragma unroll
            for (int d = 0; d < 8; ++d)
                xd[d] = (double)xls[cl * XSTRIDE + lane * 9 + d];
            unsigned code = 0;
#pragma unroll
            for (int k = 0; k < K15_; ++k) {
                double p = -Tc[k];
#pragma unroll
                for (int d = 0; d < 8; ++d) p = fma(xd[d], Sc[k * 8 + d], p);
                code |= (p > 0.0) ? (1u << k) : 0u;
            }
            idsh[lane * 68 + c] = amap[code];
        }
    }
    __syncthreads();

    // pack: idxo rows (16B per thread) + pair codes (8B per thread)
    int bb = threadIdx.x >> 2;
    int q = threadIdx.x & 3;
    {
        uint32_t w0 = *(const uint32_t*)&idsh[bb * 68 + q * 16 + 0];
        uint32_t w1 = *(const uint32_t*)&idsh[bb * 68 + q * 16 + 4];
        uint32_t w2 = *(const uint32_t*)&idsh[bb * 68 + q * 16 + 8];
        uint32_t w3 = *(const uint32_t*)&idsh[bb * 68 + q * 16 + 12];
        uint32_t* o = (uint32_t*)(idxo + (size_t)(b0 + bb) * 64 + q * 16);
        o[0] = w0; o[1] = w1; o[2] = w2; o[3] = w3;
    }
    {
        int p0 = q * 8;
        union { uint8_t b[8]; uint32_t w[2]; } u;
#pragma unroll
        for (int i = 0; i < 8; ++i) {
            int p = p0 + i;
            u.b[i] = (uint8_t)((idsh[bb * 68 + 2 * p] << 4) |
                               idsh[bb * 68 + 2 * p + 1]);
        }
        uint32_t* o = (uint32_t*)(pco + (size_t)(b0 + bb) * 32 + p0);
        o[0] = u.w[0]; o[1] = u.w[1];
    }
}

// ---------------------------------------------------------------------------
// pair table (fp16): P[p][t0*16+t1][j] = LUT[2p][t0][j]+LUT[2p+1][t1][j]
// ---------------------------------------------------------------------------
__global__ __launch_bounds__(256) void k_pairs(const float* __restrict__ LUT,
                                               _Float16* __restrict__ P) {
    int gid = blockIdx.x * 256 + threadIdx.x;  // over half8 chunks
    int j8 = gid & 63;
    int q = (gid >> 6) & 255;
    int p = gid >> 14;
    const float* u = LUT + (size_t)((p * 2) * 16 + (q >> 4)) * 512 + j8 * 8;
    const float* v = LUT + (size_t)((p * 2 + 1) * 16 + (q & 15)) * 512 + j8 * 8;
    float4 u0 = ((const float4*)u)[0];
    float4 u1 = ((const float4*)u)[1];
    float4 v0 = ((const float4*)v)[0];
    float4 v1 = ((const float4*)v)[1];
    half8 w;
    w[0] = (_Float16)(u0.x + v0.x);
    w[1] = (_Float16)(u0.y + v0.y);
    w[2] = (_Float16)(u0.z + v0.z);
    w[3] = (_Float16)(u0.w + v0.w);
    w[4] = (_Float16)(u1.x + v1.x);
    w[5] = (_Float16)(u1.y + v1.y);
    w[6] = (_Float16)(u1.z + v1.z);
    w[7] = (_Float16)(u1.w + v1.w);
    *(half8*)(P + (size_t)gid * 8) = w;
}

// ---------------------------------------------------------------------------
// k_main3: out[b][:] = sum over 32 pairs of P[p][pc[b][p]][:]
// Pairs outer (all 2048 blocks sweep the 8.4MB table in lockstep -> L2-hot),
// register double-buffer prefetch (load p+1 while accumulating p), 4 rows
// per wave, 16 rows per block.
// ---------------------------------------------------------------------------
__global__ __launch_bounds__(256) void k_main3(const uint8_t* __restrict__ pc,
                                               const _Float16* __restrict__ P,
                                               float* __restrict__ out) {
    __shared__ uint8_t pcs[512];  // 16 rows x 32 pair codes
    int b0 = blockIdx.x * 16;
    if (threadIdx.x < 128)
        ((uint32_t*)pcs)[threadIdx.x] =
            ((const uint32_t*)(pc + (size_t)b0 * 32))[threadIdx.x];
    __syncthreads();

    int jt = threadIdx.x & 63;
    int wv = threadIdx.x >> 6;
    const uint8_t* my = pcs + wv * 4 * 32;  // this wave's 4 rows

    float acc[4][8];
#pragma unroll
    for (int r = 0; r < 4; ++r)
#pragma unroll
        for (int e = 0; e < 8; ++e) acc[r][e] = 0.f;

    const _Float16* Pj = P + jt * 8;
    half8 buf[2][4];
#pragma unroll
    for (int r = 0; r < 4; ++r)
        buf[0][r] = *(const half8*)(Pj + ((size_t)my[r * 32] << 9));

#pragma unroll
    for (int p = 0; p < 32; ++p) {
        int cur = p & 1;
        int nxt = cur ^ 1;
        if (p < 31) {
            const _Float16* Pp1 = Pj + ((size_t)(p + 1) << 17);
#pragma unroll
            for (int r = 0; r < 4; ++r)
                buf[nxt][r] =
                    *(const half8*)(Pp1 + ((size_t)my[r * 32 + p + 1] << 9));
        }
#pragma unroll
        for (int r = 0; r < 4; ++r)
#pragma unroll
            for (int e = 0; e < 8; ++e) acc[r][e] += (float)buf[cur][r][e];
    }

#pragma unroll
    for (int r = 0; r < 4; ++r) {
        float* o = out + ((size_t)(b0 + wv * 4 + r)) * 512 + jt * 8;
        float4 w0;
        w0.x = acc[r][0]; w0.y = acc[r][1]; w0.z = acc[r][2]; w0.w = acc[r][3];
        float4 w1;
        w1.x = acc[r][4]; w1.y = acc[r][5]; w1.z = acc[r][6]; w1.w = acc[r][7];
        ((float4*)o)[0] = w0;
        ((float4*)o)[1] = w1;
    }
}

// Fallback (small ws): direct 64-channel gather from fp32 LUT.
__global__ __launch_bounds__(256) void k_main_direct(const uint8_t* __restrict__ idx,
                                                     const float* __restrict__ LUT,
                                                     float* __restrict__ out) {
    int j4 = threadIdx.x & 127;
    int sub = threadIdx.x >> 7;
    int b0 = blockIdx.x * 16 + sub * 8;
    const float4* L4 = (const float4*)LUT;
    for (int r = 0; r < 8; ++r) {
        int b = b0 + r;
        const uint32_t* iw = (const uint32_t*)(idx + (size_t)b * 64);
        float4 acc;
        acc.x = 0.f; acc.y = 0.f; acc.z = 0.f; acc.w = 0.f;
#pragma unroll
        for (int i = 0; i < 16; ++i) {
            uint32_t w = __builtin_amdgcn_readfirstlane(iw[i]);
#pragma unroll
            for (int t = 0; t < 4; ++t) {
                int c = i * 4 + t;
                uint32_t codev = (w >> (8 * t)) & 0xFu;
                float4 v = L4[(size_t)(c * 16 + codev) * 128 + j4];
                acc.x += v.x; acc.y += v.y; acc.z += v.z; acc.w += v.w;
            }
        }
        ((float4*)(out + (size_t)b * 512))[j4] = acc;
    }
}

extern "C" void kernel_launch(void* const* d_in, const int* in_sizes, int n_in,
                              void* d_out, int out_size, void* d_ws, size_t ws_size,
                              hipStream_t stream) {
    const float* x   = (const float*)d_in[0];
    const float* S   = (const float*)d_in[1];
    const float* H   = (const float*)d_in[2];
    const float* T   = (const float*)d_in[3];
    const float* LUT = (const float*)d_in[4];
    float* out = (float*)d_out;

    uint8_t* ws = (uint8_t*)d_ws;
    uint8_t* amap = ws + AMAP_OFF;
    double* S64   = (double*)(ws + S64_OFF);
    double* T64   = (double*)(ws + T64_OFF);
    uint8_t* idxb = ws + IDX_OFF;
    uint8_t* pcb  = ws + PC_OFF;
    _Float16* P   = (_Float16*)(ws + PTAB_OFF);

    bool use_pairs = ws_size >= WS_NEED;

    hipLaunchKernelGGL(k_amap, dim3(32768 / 256), dim3(256), 0, stream, H, amap);
    hipLaunchKernelGGL(k_prep, dim3(1), dim3(256), 0, stream, S, T, S64, T64);
    if (use_pairs) {
        hipLaunchKernelGGL(k_pairs, dim3(2048), dim3(256), 0, stream, LUT, P);
    }
    hipLaunchKernelGGL(k_codes2, dim3(B_ / 64), dim3(256), 0, stream,
                       x, S64, T64, amap, idxb, pcb);
    if (use_pairs) {
        hipLaunchKernelGGL(k_main3, dim3(B_ / 16), dim3(256), 0, stream,
                           pcb, P, out);
    } else {
        hipLaunchKernelGGL(k_main_direct, dim3(B_ / 16), dim3(256), 0, stream,
                           idxb, LUT, out);
    }
}

// Round 4
// 211.575 us; speedup vs baseline: 1.3255x; 1.3255x over previous
//
#include <hip/hip_runtime.h>
#include <stdint.h>

#define B_    32768
#define C_    64
#define D_    8
#define K15_  15
#define K16_  16
#define OUT_  512

typedef _Float16 half4v __attribute__((ext_vector_type(4)));
typedef _Float16 half8  __attribute__((ext_vector_type(8)));

// workspace layout (bytes)
#define AMAP_OFF  0
#define AMAP_SZ   32768                  // uint8 argmax per 15-bit code
#define S64_OFF   32768                  // fp64 S, k-major: S64[c][k][d]
#define S64_SZ    (64 * 15 * 8 * 8)      // 61440
#define T64_OFF   (S64_OFF + S64_SZ)     // 94208
#define T64_SZ    (64 * 15 * 8)          // 7680
#define IDX_OFF   (T64_OFF + T64_SZ)     // 101888
#define IDX_SZ    (B_ * C_)              // 2 MB
#define PC_OFF    (IDX_OFF + IDX_SZ)     // 2199040
#define PC_SZ     (B_ * 32)              // 1 MB
#define PTAB_OFF  (PC_OFF + PC_SZ)       // 3247616 (16B aligned)
#define PTAB_SZ   (32 * 256 * 512 * 2)   // 8388608  P[pair][t0t1][512] fp16
#define WS_NEED   ((size_t)PTAB_OFF + PTAB_SZ)

// ---------------------------------------------------------------------------
// k_setup (fused): every block writes its slice of the fp16 pair table;
// blocks 0..127 additionally compute amap (1 code/thread); block 128 builds
// the fp64 k-major S64/T64 tables. All parts independent.
// ---------------------------------------------------------------------------
__global__ __launch_bounds__(256) void k_setup(const float* __restrict__ LUT,
                                               const float* __restrict__ H,
                                               const float* __restrict__ S,
                                               const float* __restrict__ T,
                                               _Float16* __restrict__ P,
                                               uint8_t* __restrict__ amap,
                                               double* __restrict__ S64,
                                               double* __restrict__ T64,
                                               int do_pairs) {
    int gid = blockIdx.x * 256 + threadIdx.x;

    if (do_pairs) {
        int j8 = gid & 63;
        int q = (gid >> 6) & 255;
        int p = gid >> 14;
        const float* u = LUT + (size_t)((p * 2) * 16 + (q >> 4)) * 512 + j8 * 8;
        const float* v = LUT + (size_t)((p * 2 + 1) * 16 + (q & 15)) * 512 + j8 * 8;
        float4 u0 = ((const float4*)u)[0];
        float4 u1 = ((const float4*)u)[1];
        float4 v0 = ((const float4*)v)[0];
        float4 v1 = ((const float4*)v)[1];
        half8 w;
        w[0] = (_Float16)(u0.x + v0.x);
        w[1] = (_Float16)(u0.y + v0.y);
        w[2] = (_Float16)(u0.z + v0.z);
        w[3] = (_Float16)(u0.w + v0.w);
        w[4] = (_Float16)(u1.x + v1.x);
        w[5] = (_Float16)(u1.y + v1.y);
        w[6] = (_Float16)(u1.z + v1.z);
        w[7] = (_Float16)(u1.w + v1.w);
        *(half8*)(P + (size_t)gid * 8) = w;
    }

    if (blockIdx.x < 128) {
        int code = gid;
        double h[K16_];
#pragma unroll
        for (int j = 0; j < K16_; ++j) h[j] = 0.0;
#pragma unroll
        for (int k = 0; k < K15_; ++k) {
            double s = ((code >> k) & 1) ? 1.0 : -1.0;
#pragma unroll
            for (int j = 0; j < K16_; ++j) h[j] += s * (double)H[k * K16_ + j];
        }
        double best = h[0];
        int bi = 0;
#pragma unroll
        for (int j = 1; j < K16_; ++j) {
            if (h[j] > best) { best = h[j]; bi = j; }
        }
        amap[code] = (uint8_t)bi;
    } else if (blockIdx.x == 128) {
        for (int i = threadIdx.x; i < 64 * 15 * 8; i += 256) {
            int c = i / 120;
            int r = i - c * 120;  // r = k*8 + d
            int k = r >> 3;
            int d = r & 7;
            S64[i] = (double)S[c * 120 + d * 15 + k];
        }
        for (int i = threadIdx.x; i < 64 * 15; i += 256) T64[i] = (double)T[i];
    }
}

// ---------------------------------------------------------------------------
// k_codes2: block = 256 thr (4 waves), 64 batches per block.
// Stage x into LDS transposed, wave<->channel, lane<->batch: S/T wave-uniform
// scalar loads; fp64 dot products. Writes idx bytes + packed pair codes.
// ---------------------------------------------------------------------------
#define XSTRIDE 585   // odd -> conflict-free
__global__ __launch_bounds__(256) void k_codes2(const float* __restrict__ x,
                                                const double* __restrict__ S64,
                                                const double* __restrict__ T64,
                                                const uint8_t* __restrict__ amap,
                                                uint8_t* __restrict__ idxo,
                                                uint8_t* __restrict__ pco) {
    __shared__ float xls[32 * XSTRIDE];
    __shared__ uint8_t idsh[64 * 68];

    int b0 = blockIdx.x * 64;
    int lane = threadIdx.x & 63;
    int wv = __builtin_amdgcn_readfirstlane(threadIdx.x >> 6);

    for (int half = 0; half < 2; ++half) {
        __syncthreads();
#pragma unroll
        for (int t = 0; t < 16; ++t) {
            int e = t * 256 + threadIdx.x;
            int b = e >> 6;
            int j4 = e & 63;
            float4 v = ((const float4*)(x + (size_t)(b0 + b) * 512 +
                                        half * 256))[j4];
            int cl = j4 >> 1;
            int d0 = (j4 & 1) * 4;
            float* dst = &xls[cl * XSTRIDE + b * 9 + d0];
            dst[0] = v.x; dst[1] = v.y; dst[2] = v.z; dst[3] = v.w;
        }
        __syncthreads();
        for (int i = 0; i < 8; ++i) {
            int cl = wv + i * 4;                 // wave-uniform
            int c = half * 32 + cl;
            const double* Sc = S64 + c * 120;    // k-major: Sc[k*8+d]
            const double* Tc = T64 + c * 15;
            double xd[8];
#pragma unroll
            for (int d = 0; d < 8; ++d)
                xd[d] = (double)xls[cl * XSTRIDE + lane * 9 + d];
            unsigned code = 0;
#pragma unroll
            for (int k = 0; k < K15_; ++k) {
                double p = -Tc[k];
#pragma unroll
                for (int d = 0; d < 8; ++d) p = fma(xd[d], Sc[k * 8 + d], p);
                code |= (p > 0.0) ? (1u << k) : 0u;
            }
            idsh[lane * 68 + c] = amap[code];
        }
    }
    __syncthreads();

    int bb = threadIdx.x >> 2;
    int q = threadIdx.x & 3;
    {
        uint32_t w0 = *(const uint32_t*)&idsh[bb * 68 + q * 16 + 0];
        uint32_t w1 = *(const uint32_t*)&idsh[bb * 68 + q * 16 + 4];
        uint32_t w2 = *(const uint32_t*)&idsh[bb * 68 + q * 16 + 8];
        uint32_t w3 = *(const uint32_t*)&idsh[bb * 68 + q * 16 + 12];
        uint32_t* o = (uint32_t*)(idxo + (size_t)(b0 + bb) * 64 + q * 16);
        o[0] = w0; o[1] = w1; o[2] = w2; o[3] = w3;
    }
    {
        int p0 = q * 8;
        union { uint8_t b[8]; uint32_t w[2]; } u;
#pragma unroll
        for (int i = 0; i < 8; ++i) {
            int p = p0 + i;
            u.b[i] = (uint8_t)((idsh[bb * 68 + 2 * p] << 4) |
                               idsh[bb * 68 + 2 * p + 1]);
        }
        uint32_t* o = (uint32_t*)(pco + (size_t)(b0 + bb) * 32 + p0);
        o[0] = u.w[0]; o[1] = u.w[1];
    }
}

// ---------------------------------------------------------------------------
// k_main4: out[b][:] = sum over 32 pairs of P[p][pc[b][p]][:]
// Grid 1024 blocks (exactly 4/CU, ALL co-resident at 4 waves/SIMD ->
// lockstep table sweep stays inside L2). Block = 32 rows; wave = 16 rows x
// 4 halfs (8B loads, 16 in flight). Codes are wave-uniform: LDS b128
// broadcast + readfirstlane -> address math on SALU; VALU only accumulates.
// ---------------------------------------------------------------------------
__global__ __launch_bounds__(256, 4) void k_main4(const uint8_t* __restrict__ pc,
                                                  const _Float16* __restrict__ P,
                                                  float* __restrict__ out) {
    __shared__ __align__(16) uint8_t pcT[32 * 32];  // [pair][row]
    int b0 = blockIdx.x * 32;
    {
        int row = threadIdx.x & 31;
        int g = threadIdx.x >> 5;  // 8 groups of 4 pairs
        uint32_t w = *(const uint32_t*)(pc + (size_t)(b0 + row) * 32 + g * 4);
#pragma unroll
        for (int i = 0; i < 4; ++i)
            pcT[(g * 4 + i) * 32 + row] = (uint8_t)(w >> (8 * i));
    }
    __syncthreads();

    int lane = threadIdx.x & 63;
    int wv = threadIdx.x >> 6;
    int jh = wv & 1;       // j-half: elements [jh*256, jh*256+256)
    int rgrp = wv >> 1;    // rows [rgrp*16, rgrp*16+16)

    float acc[16][4];
#pragma unroll
    for (int r = 0; r < 16; ++r)
#pragma unroll
        for (int e = 0; e < 4; ++e) acc[r][e] = 0.f;

    const _Float16* Pl = P + jh * 256 + lane * 4;

    for (int p = 0; p < 32; ++p) {
        uint4 cwv = *(const uint4*)(pcT + p * 32 + rgrp * 16);  // broadcast
        uint32_t cw[4];
        cw[0] = __builtin_amdgcn_readfirstlane(cwv.x);
        cw[1] = __builtin_amdgcn_readfirstlane(cwv.y);
        cw[2] = __builtin_amdgcn_readfirstlane(cwv.z);
        cw[3] = __builtin_amdgcn_readfirstlane(cwv.w);
        const _Float16* Pp = Pl + ((size_t)p << 17);
        half4v h[16];
#pragma unroll
        for (int r = 0; r < 16; ++r) {
            uint32_t code = (cw[r >> 2] >> ((r & 3) * 8)) & 0xFFu;
            h[r] = *(const half4v*)(Pp + ((size_t)code << 9));
        }
#pragma unroll
        for (int r = 0; r < 16; ++r)
#pragma unroll
            for (int e = 0; e < 4; ++e) acc[r][e] += (float)h[r][e];
    }

#pragma unroll
    for (int r = 0; r < 16; ++r) {
        float4 w;
        w.x = acc[r][0]; w.y = acc[r][1]; w.z = acc[r][2]; w.w = acc[r][3];
        *(float4*)(out + (size_t)(b0 + rgrp * 16 + r) * 512 + jh * 256 +
                   lane * 4) = w;
    }
}

// Fallback (small ws): direct 64-channel gather from fp32 LUT.
__global__ __launch_bounds__(256) void k_main_direct(const uint8_t* __restrict__ idx,
                                                     const float* __restrict__ LUT,
                                                     float* __restrict__ out) {
    int j4 = threadIdx.x & 127;
    int sub = threadIdx.x >> 7;
    int b0 = blockIdx.x * 16 + sub * 8;
    const float4* L4 = (const float4*)LUT;
    for (int r = 0; r < 8; ++r) {
        int b = b0 + r;
        const uint32_t* iw = (const uint32_t*)(idx + (size_t)b * 64);
        float4 acc;
        acc.x = 0.f; acc.y = 0.f; acc.z = 0.f; acc.w = 0.f;
#pragma unroll
        for (int i = 0; i < 16; ++i) {
            uint32_t w = __builtin_amdgcn_readfirstlane(iw[i]);
#pragma unroll
            for (int t = 0; t < 4; ++t) {
                int c = i * 4 + t;
                uint32_t codev = (w >> (8 * t)) & 0xFu;
                float4 v = L4[(size_t)(c * 16 + codev) * 128 + j4];
                acc.x += v.x; acc.y += v.y; acc.z += v.z; acc.w += v.w;
            }
        }
        ((float4*)(out + (size_t)b * 512))[j4] = acc;
    }
}

extern "C" void kernel_launch(void* const* d_in, const int* in_sizes, int n_in,
                              void* d_out, int out_size, void* d_ws, size_t ws_size,
                              hipStream_t stream) {
    const float* x   = (const float*)d_in[0];
    const float* S   = (const float*)d_in[1];
    const float* H   = (const float*)d_in[2];
    const float* T   = (const float*)d_in[3];
    const float* LUT = (const float*)d_in[4];
    float* out = (float*)d_out;

    uint8_t* ws = (uint8_t*)d_ws;
    uint8_t* amap = ws + AMAP_OFF;
    double* S64   = (double*)(ws + S64_OFF);
    double* T64   = (double*)(ws + T64_OFF);
    uint8_t* idxb = ws + IDX_OFF;
    uint8_t* pcb  = ws + PC_OFF;
    _Float16* P   = (_Float16*)(ws + PTAB_OFF);

    bool use_pairs = ws_size >= WS_NEED;

    // fused setup: pair table + amap + S64/T64
    hipLaunchKernelGGL(k_setup, dim3(use_pairs ? 2048 : 129), dim3(256), 0,
                       stream, LUT, H, S, T, P, amap, S64, T64,
                       use_pairs ? 1 : 0);
    hipLaunchKernelGGL(k_codes2, dim3(B_ / 64), dim3(256), 0, stream,
                       x, S64, T64, amap, idxb, pcb);
    if (use_pairs) {
        hipLaunchKernelGGL(k_main4, dim3(B_ / 32), dim3(256), 0, stream,
                           pcb, P, out);
    } else {
        hipLaunchKernelGGL(k_main_direct, dim3(B_ / 16), dim3(256), 0, stream,
                           idxb, LUT, out);
    }
}

// Round 5
// 206.363 us; speedup vs baseline: 1.3590x; 1.0253x over previous
//
#include <hip/hip_runtime.h>
#include <stdint.h>

#define B_    32768
#define C_    64
#define D_    8
#define K15_  15
#define K16_  16
#define OUT_  512

typedef _Float16 half4v __attribute__((ext_vector_type(4)));
typedef _Float16 half8  __attribute__((ext_vector_type(8)));

// workspace layout (bytes)
#define AMAP_OFF  0
#define AMAP_SZ   32768                  // uint8 argmax per 15-bit code
#define S64_OFF   32768                  // fp64 S, k-major: S64[c][k][d]
#define S64_SZ    (64 * 15 * 8 * 8)      // 61440
#define T64_OFF   (S64_OFF + S64_SZ)     // 94208
#define T64_SZ    (64 * 15 * 8)          // 7680
#define IDX_OFF   (T64_OFF + T64_SZ)     // 101888
#define IDX_SZ    (B_ * C_)              // 2 MB
#define PCT_OFF   (IDX_OFF + IDX_SZ)     // 2199040
#define PCT_SZ    (B_ * 32)              // 1 MB: pcT[p][rg][tr][i]
#define PTAB_OFF  (PCT_OFF + PCT_SZ)     // 3247616 (16B aligned)
#define PTAB_SZ   (32 * 32 * 256 * 16 * 2) // 8388608: P5[p][jc][q][16] fp16
#define WS_NEED   ((size_t)PTAB_OFF + PTAB_SZ)

// ---------------------------------------------------------------------------
// k_setup (fused): 2048 blocks write P5 (j-first layout, fully coalesced
// 16B stores); blocks 0..127 also compute amap; block 128 builds S64/T64.
// P5 half-index: ((p*32 + jc)*256 + q)*16 + e   (q = (t0<<4)|t1)
// ---------------------------------------------------------------------------
__global__ __launch_bounds__(256) void k_setup(const float* __restrict__ LUT,
                                               const float* __restrict__ H,
                                               const float* __restrict__ S,
                                               const float* __restrict__ T,
                                               _Float16* __restrict__ P5,
                                               uint8_t* __restrict__ amap,
                                               double* __restrict__ S64,
                                               double* __restrict__ T64,
                                               int do_pairs) {
    int gid = blockIdx.x * 256 + threadIdx.x;

    if (do_pairs) {
        // gid bits: [p:5][jc:5][q:8][e8:1] -> write offset = gid*8 halfs
        int e8 = gid & 1;
        int q = (gid >> 1) & 255;
        int jc = (gid >> 9) & 31;
        int p = gid >> 14;
        int t0 = q >> 4;
        int t1 = q & 15;
        int j0 = jc * 16 + e8 * 8;
        const float* u = LUT + (size_t)((2 * p) * 16 + t0) * 512 + j0;
        const float* v = LUT + (size_t)((2 * p + 1) * 16 + t1) * 512 + j0;
        float4 u0 = ((const float4*)u)[0];
        float4 u1 = ((const float4*)u)[1];
        float4 v0 = ((const float4*)v)[0];
        float4 v1 = ((const float4*)v)[1];
        half8 w;
        w[0] = (_Float16)(u0.x + v0.x);
        w[1] = (_Float16)(u0.y + v0.y);
        w[2] = (_Float16)(u0.z + v0.z);
        w[3] = (_Float16)(u0.w + v0.w);
        w[4] = (_Float16)(u1.x + v1.x);
        w[5] = (_Float16)(u1.y + v1.y);
        w[6] = (_Float16)(u1.z + v1.z);
        w[7] = (_Float16)(u1.w + v1.w);
        *(half8*)(P5 + (size_t)gid * 8) = w;
    }

    if (blockIdx.x < 128) {
        int code = gid;
        double h[K16_];
#pragma unroll
        for (int j = 0; j < K16_; ++j) h[j] = 0.0;
#pragma unroll
        for (int k = 0; k < K15_; ++k) {
            double s = ((code >> k) & 1) ? 1.0 : -1.0;
#pragma unroll
            for (int j = 0; j < K16_; ++j) h[j] += s * (double)H[k * K16_ + j];
        }
        double best = h[0];
        int bi = 0;
#pragma unroll
        for (int j = 1; j < K16_; ++j) {
            if (h[j] > best) { best = h[j]; bi = j; }
        }
        amap[code] = (uint8_t)bi;
    } else if (blockIdx.x == 128) {
        for (int i = threadIdx.x; i < 64 * 15 * 8; i += 256) {
            int c = i / 120;
            int r = i - c * 120;  // r = k*8 + d
            int k = r >> 3;
            int d = r & 7;
            S64[i] = (double)S[c * 120 + d * 15 + k];
        }
        for (int i = threadIdx.x; i < 64 * 15; i += 256) T64[i] = (double)T[i];
    }
}

// ---------------------------------------------------------------------------
// k_codes2: block = 256 thr (4 waves), 64 batches per block.
// Stage x into LDS transposed, wave<->channel, lane<->batch: S/T wave-uniform
// scalar loads; fp64 dot products. Writes idx bytes + transposed pair codes
// pcT[p][rg=row>>10][tr=row&127][i=(row&1023)>>7].
// ---------------------------------------------------------------------------
#define XSTRIDE 585   // odd -> conflict-free
__global__ __launch_bounds__(256) void k_codes2(const float* __restrict__ x,
                                                const double* __restrict__ S64,
                                                const double* __restrict__ T64,
                                                const uint8_t* __restrict__ amap,
                                                uint8_t* __restrict__ idxo,
                                                uint8_t* __restrict__ pcT) {
    __shared__ float xls[32 * XSTRIDE];
    __shared__ uint8_t idsh[64 * 68];

    int b0 = blockIdx.x * 64;
    int lane = threadIdx.x & 63;
    int wv = __builtin_amdgcn_readfirstlane(threadIdx.x >> 6);

    for (int half = 0; half < 2; ++half) {
        __syncthreads();
#pragma unroll
        for (int t = 0; t < 16; ++t) {
            int e = t * 256 + threadIdx.x;
            int b = e >> 6;
            int j4 = e & 63;
            float4 v = ((const float4*)(x + (size_t)(b0 + b) * 512 +
                                        half * 256))[j4];
            int cl = j4 >> 1;
            int d0 = (j4 & 1) * 4;
            float* dst = &xls[cl * XSTRIDE + b * 9 + d0];
            dst[0] = v.x; dst[1] = v.y; dst[2] = v.z; dst[3] = v.w;
        }
        __syncthreads();
        for (int i = 0; i < 8; ++i) {
            int cl = wv + i * 4;                 // wave-uniform
            int c = half * 32 + cl;
            const double* Sc = S64 + c * 120;    // k-major: Sc[k*8+d]
            const double* Tc = T64 + c * 15;
            double xd[8];
#pragma unroll
            for (int d = 0; d < 8; ++d)
                xd[d] = (double)xls[cl * XSTRIDE + lane * 9 + d];
            unsigned code = 0;
#pragma unroll
            for (int k = 0; k < K15_; ++k) {
                double p = -Tc[k];
#pragma unroll
                for (int d = 0; d < 8; ++d) p = fma(xd[d], Sc[k * 8 + d], p);
                code |= (p > 0.0) ? (1u << k) : 0u;
            }
            idsh[lane * 68 + c] = amap[code];
        }
    }
    __syncthreads();

    int bb = threadIdx.x >> 2;
    int q = threadIdx.x & 3;
    {
        uint32_t w0 = *(const uint32_t*)&idsh[bb * 68 + q * 16 + 0];
        uint32_t w1 = *(const uint32_t*)&idsh[bb * 68 + q * 16 + 4];
        uint32_t w2 = *(const uint32_t*)&idsh[bb * 68 + q * 16 + 8];
        uint32_t w3 = *(const uint32_t*)&idsh[bb * 68 + q * 16 + 12];
        uint32_t* o = (uint32_t*)(idxo + (size_t)(b0 + bb) * 64 + q * 16);
        o[0] = w0; o[1] = w1; o[2] = w2; o[3] = w3;
    }
    {
        int row = b0 + bb;
        int rg = row >> 10;
        int tr = row & 127;
        int i_ = (row & 1023) >> 7;
        uint8_t* base = pcT + rg * 1024 + tr * 8 + i_;
#pragma unroll
        for (int pi = 0; pi < 8; ++pi) {
            int p = q * 8 + pi;
            uint8_t byte = (uint8_t)((idsh[bb * 68 + 2 * p] << 4) |
                                     idsh[bb * 68 + 2 * p + 1]);
            base[p * 32768] = byte;
        }
    }
}

// ---------------------------------------------------------------------------
// k_main5: streaming-staged gather.
// Block (rg = blk>>5, jc = blk&31) owns 1024 rows x 16 output halfs.
// Per pair p: stream the 8KB slab P5[p][jc][*][16] into LDS (pad to 20 halfs
// per code -> b64 reads spread over all 16 bank-pairs), then each thread
// gathers 8 rows x 8 halfs from LDS and fma_mix-accumulates in fp32.
// Slab + codes for p+1 are register-prefetched during gather of p.
// jc = blk&31 pins all 32 rg-readers of a slab to one XCD's L2.
// ---------------------------------------------------------------------------
__global__ __launch_bounds__(256, 4) void k_main5(const uint8_t* __restrict__ pcT,
                                                  const _Float16* __restrict__ P5,
                                                  float* __restrict__ out) {
    __shared__ _Float16 slab[256 * 20];  // 40 B per code row (16 used + pad)

    int rg = blockIdx.x >> 5;
    int jc = blockIdx.x & 31;
    int t = threadIdx.x;
    int tc = t & 1;        // which 8-half piece of the 16-half chunk
    int tr = t >> 1;       // 0..127, rows tr + 128*i

    const _Float16* src0 = P5 + ((size_t)(0 * 32 + jc) * 256 + t) * 16;
    const uint8_t* cbase = pcT + rg * 1024 + tr * 8;

    float acc[8][8];
#pragma unroll
    for (int i = 0; i < 8; ++i)
#pragma unroll
        for (int e = 0; e < 8; ++e) acc[i][e] = 0.f;

    // prefetch p=0
    half8 g0 = ((const half8*)src0)[0];
    half8 g1 = ((const half8*)src0)[1];
    uint64_t cw = *(const uint64_t*)cbase;

    for (int p = 0; p < 32; ++p) {
        __syncthreads();  // previous gather done; slab reusable
        {
            _Float16* d = slab + t * 20;
            *(half4v*)(d + 0)  = half4v{g0[0], g0[1], g0[2], g0[3]};
            *(half4v*)(d + 4)  = half4v{g0[4], g0[5], g0[6], g0[7]};
            *(half4v*)(d + 8)  = half4v{g1[0], g1[1], g1[2], g1[3]};
            *(half4v*)(d + 12) = half4v{g1[4], g1[5], g1[6], g1[7]};
        }
        __syncthreads();  // slab ready

        if (p < 31) {  // prefetch p+1 while gathering p
            const _Float16* srcn =
                P5 + ((size_t)((p + 1) * 32 + jc) * 256 + t) * 16;
            g0 = ((const half8*)srcn)[0];
            g1 = ((const half8*)srcn)[1];
        }
        uint64_t cw_cur = cw;
        if (p < 31) cw = *(const uint64_t*)(cbase + (size_t)(p + 1) * 32768);

#pragma unroll
        for (int i = 0; i < 8; ++i) {
            int ci = (int)((cw_cur >> (8 * i)) & 0xFF);
            const _Float16* s = slab + ci * 20 + tc * 8;
            half4v a = *(const half4v*)(s + 0);
            half4v b = *(const half4v*)(s + 4);
#pragma unroll
            for (int e = 0; e < 4; ++e) acc[i][e] += (float)a[e];
#pragma unroll
            for (int e = 0; e < 4; ++e) acc[i][4 + e] += (float)b[e];
        }
    }

#pragma unroll
    for (int i = 0; i < 8; ++i) {
        int row = rg * 1024 + i * 128 + tr;
        float* o = out + (size_t)row * 512 + jc * 16 + tc * 8;
        float4 w0;
        w0.x = acc[i][0]; w0.y = acc[i][1]; w0.z = acc[i][2]; w0.w = acc[i][3];
        float4 w1;
        w1.x = acc[i][4]; w1.y = acc[i][5]; w1.z = acc[i][6]; w1.w = acc[i][7];
        ((float4*)o)[0] = w0;
        ((float4*)o)[1] = w1;
    }
}

// Fallback (small ws): direct 64-channel gather from fp32 LUT.
__global__ __launch_bounds__(256) void k_main_direct(const uint8_t* __restrict__ idx,
                                                     const float* __restrict__ LUT,
                                                     float* __restrict__ out) {
    int j4 = threadIdx.x & 127;
    int sub = threadIdx.x >> 7;
    int b0 = blockIdx.x * 16 + sub * 8;
    const float4* L4 = (const float4*)LUT;
    for (int r = 0; r < 8; ++r) {
        int b = b0 + r;
        const uint32_t* iw = (const uint32_t*)(idx + (size_t)b * 64);
        float4 acc;
        acc.x = 0.f; acc.y = 0.f; acc.z = 0.f; acc.w = 0.f;
#pragma unroll
        for (int i = 0; i < 16; ++i) {
            uint32_t w = __builtin_amdgcn_readfirstlane(iw[i]);
#pragma unroll
            for (int t = 0; t < 4; ++t) {
                int c = i * 4 + t;
                uint32_t codev = (w >> (8 * t)) & 0xFu;
                float4 v = L4[(size_t)(c * 16 + codev) * 128 + j4];
                acc.x += v.x; acc.y += v.y; acc.z += v.z; acc.w += v.w;
            }
        }
        ((float4*)(out + (size_t)b * 512))[j4] = acc;
    }
}

extern "C" void kernel_launch(void* const* d_in, const int* in_sizes, int n_in,
                              void* d_out, int out_size, void* d_ws, size_t ws_size,
                              hipStream_t stream) {
    const float* x   = (const float*)d_in[0];
    const float* S   = (const float*)d_in[1];
    const float* H   = (const float*)d_in[2];
    const float* T   = (const float*)d_in[3];
    const float* LUT = (const float*)d_in[4];
    float* out = (float*)d_out;

    uint8_t* ws = (uint8_t*)d_ws;
    uint8_t* amap = ws + AMAP_OFF;
    double* S64   = (double*)(ws + S64_OFF);
    double* T64   = (double*)(ws + T64_OFF);
    uint8_t* idxb = ws + IDX_OFF;
    uint8_t* pcTb = ws + PCT_OFF;
    _Float16* P5  = (_Float16*)(ws + PTAB_OFF);

    bool use_pairs = ws_size >= WS_NEED;

    hipLaunchKernelGGL(k_setup, dim3(use_pairs ? 2048 : 129), dim3(256), 0,
                       stream, LUT, H, S, T, P5, amap, S64, T64,
                       use_pairs ? 1 : 0);
    hipLaunchKernelGGL(k_codes2, dim3(B_ / 64), dim3(256), 0, stream,
                       x, S64, T64, amap, idxb, pcTb);
    if (use_pairs) {
        hipLaunchKernelGGL(k_main5, dim3(1024), dim3(256), 0, stream,
                           pcTb, P5, out);
    } else {
        hipLaunchKernelGGL(k_main_direct, dim3(B_ / 16), dim3(256), 0, stream,
                           idxb, LUT, out);
    }
}